// Round 1
// baseline (1628.623 us; speedup 1.0000x reference)
//
#include <hip/hip_runtime.h>
#include <hip/hip_bf16.h>
#include <cstdint>

// Problem constants (B,C,H,W fixed by setup_inputs)
constexpr int NB = 4;
constexpr int NC = 64;
constexpr int NH = 96;
constexpr int NW = 256;
constexpr int HWp = NH * NW;          // 24576 pixels per plane
constexpr int NM = 4;                 // SKM branches, dilation 2*(m+1)
constexpr float EPS = 1e-6f;

// ---------------------------------------------------------------------------
// LayerNorm2d over channels at each (b,h,w). Block = one (b,h) row, 256 thr.
// ---------------------------------------------------------------------------
__global__ __launch_bounds__(256) void k_ln(const float* __restrict__ x,
                                            const float* __restrict__ g,
                                            const float* __restrict__ bta,
                                            float* __restrict__ out) {
    int h = blockIdx.x, b = blockIdx.y, w = threadIdx.x;
    const float* xp = x + ((size_t)b * NC * NH + h) * NW + w;
    float v[64];
    float s = 0.f, sq = 0.f;
#pragma unroll
    for (int c = 0; c < 64; ++c) {
        float t = xp[(size_t)c * HWp];
        v[c] = t; s += t; sq += t * t;
    }
    float mu = s * (1.f / 64.f);
    float var = sq * (1.f / 64.f) - mu * mu;
    float rs = rsqrtf(var + EPS);
    float* op = out + ((size_t)b * NC * NH + h) * NW + w;
#pragma unroll
    for (int c = 0; c < 64; ++c) op[(size_t)c * HWp] = (v[c] - mu) * rs * g[c] + bta[c];
}

// ---------------------------------------------------------------------------
// Rectangle sums for the SKM global pool, done WITHOUT materializing D.
// For each (b,ci): T[m][kh][kw] = sum of xln over rows R(kh) x cols C(kw)
//   R(0)=[0,H-d) R(1)=[0,H) R(2)=[d,H), same for cols, d = 2*(m+1).
// One block per (b,ci); wave per row computes {full,L2..L8,R2..R8}.
// T layout: [b][m][ci][9]  (matches dw's (ci,kh,kw) inner order)
// ---------------------------------------------------------------------------
__global__ __launch_bounds__(256) void k_rect(const float* __restrict__ xln,
                                              float* __restrict__ T) {
    int bci = blockIdx.x;
    int b = bci >> 6, ci = bci & 63;
    int t = threadIdx.x, lane = t & 63, wv = t >> 6;
    __shared__ float rp[NH][9];
    const float* base = xln + (size_t)bci * HWp;
    for (int r = wv; r < NH; r += 4) {
        float4 vv = *(const float4*)(base + r * NW + lane * 4);
        float a = vv.x + vv.y, bb = vv.z + vv.w;
        float s4 = a + bb;
        float full = s4;
#pragma unroll
        for (int o = 32; o; o >>= 1) full += __shfl_xor(full, o, 64);
        float l0a = __shfl(a, 0, 64),  l0s = __shfl(s4, 0, 64);
        float l1a = __shfl(a, 1, 64),  l1s = __shfl(s4, 1, 64);
        float r63b = __shfl(bb, 63, 64), r63s = __shfl(s4, 63, 64);
        float r62b = __shfl(bb, 62, 64), r62s = __shfl(s4, 62, 64);
        if (lane == 0) {
            rp[r][0] = full;
            rp[r][1] = l0a;  rp[r][2] = l0s;  rp[r][3] = l0s + l1a;  rp[r][4] = l0s + l1s;
            rp[r][5] = r63b; rp[r][6] = r63s; rp[r][7] = r63s + r62b; rp[r][8] = r63s + r62s;
        }
    }
    __syncthreads();
    if (t < 36) {
        int m = t / 9, kh = (t % 9) / 3, kw = t % 3;
        int d = 2 * (m + 1);
        int r0 = (kh == 2) ? d : 0;
        int r1 = (kh == 0) ? NH - d : NH;
        float s = 0.f;
        for (int r = r0; r < r1; ++r) {
            float rowv = rp[r][0];
            if (kw == 0) rowv -= rp[r][5 + m];        // drop last d cols
            else if (kw == 2) rowv -= rp[r][1 + m];   // drop first d cols
            s += rowv;
        }
        T[(((b * 4 + m) * 64) + ci) * 9 + kh * 3 + kw] = s;
    }
}

// ---------------------------------------------------------------------------
// SKM selection MLP: Z -> S -> P -> softmax over C -> Sw, plus folded bias.
// Single block (tiny).
// ---------------------------------------------------------------------------
__global__ __launch_bounds__(256) void k_select(const float* __restrict__ T,
                                                const float* __restrict__ dw,
                                                const float* __restrict__ db,
                                                const float* __restrict__ c1w,
                                                const float* __restrict__ c1b,
                                                const float* __restrict__ pw,
                                                float* __restrict__ Sw,
                                                float* __restrict__ Qb) {
    int t = threadIdx.x;
    __shared__ float zs[256], ss[512], ps[1024], sw[1024];
    {
        int b = t >> 6, c = t & 63;
        float acc = 0.f, bias = 0.f;
        for (int m = 0; m < 4; ++m) {
            const float* wp = dw + (size_t)(m * 64 + c) * 576;
            const float* tp = T + (size_t)(b * 4 + m) * 576;
            float a2 = 0.f;
            for (int j = 0; j < 576; ++j) a2 += wp[j] * tp[j];
            acc += a2;
            bias += db[m * 64 + c];
        }
        zs[t] = acc * (1.f / (float)HWp) + bias;
    }
    __syncthreads();
    for (int i = t; i < 512; i += 256) {
        int b = i >> 7, j = i & 127;
        float s = c1b[j];
        const float* wrow = c1w + j * 64;
        const float* zb = zs + b * 64;
        for (int c = 0; c < 64; ++c) s += zb[c] * wrow[c];
        ss[i] = fmaxf(s, 0.f);
    }
    __syncthreads();
    for (int i = t; i < 1024; i += 256) {
        int b = i >> 8, rem = i & 255;
        float p = 0.f;
        const float* sb = ss + b * 128;
        for (int j = 0; j < 128; ++j) p += sb[j] * pw[j * 256 + rem];
        ps[i] = p;
    }
    __syncthreads();
    if (t < 16) {
        int b = t >> 2, m = t & 3;
        const float* pp = ps + b * 256 + m * 64;
        float mx = -1e30f;
        for (int c = 0; c < 64; ++c) mx = fmaxf(mx, pp[c]);
        float sum = 0.f;
        for (int c = 0; c < 64; ++c) sum += expf(pp[c] - mx);
        float inv = 1.f / sum;
        for (int c = 0; c < 64; ++c) sw[b * 256 + m * 64 + c] = expf(pp[c] - mx) * inv;
    }
    __syncthreads();
    {
        int b = t >> 6, c = t & 63;
        float qb = 0.f;
#pragma unroll
        for (int m = 0; m < 4; ++m) {
            float s = sw[b * 256 + m * 64 + c];
            Sw[(b * 4 + m) * 64 + c] = s;
            qb += s * db[m * 64 + c];
        }
        Qb[t] = qb;
    }
}

// ---------------------------------------------------------------------------
// Fold Sw into conv weights: Wf[b][ci][c][m*9+k] = Sw[b][m][c]*dw[m][c][ci][k]
// ---------------------------------------------------------------------------
__global__ __launch_bounds__(256) void k_fold(const float* __restrict__ dw,
                                              const float* __restrict__ Sw,
                                              float* __restrict__ Wf) {
    int idx = blockIdx.x * 256 + threadIdx.x;   // 589824 total
    int k = idx % 36;
    int r = idx / 36;
    int c = r & 63; r >>= 6;
    int ci = r & 63;
    int b = r >> 6;
    int m = k / 9, k9 = k % 9;
    Wf[idx] = Sw[(b * 4 + m) * 64 + c] * dw[(size_t)((m * 64 + c) * 64 + ci) * 9 + k9];
}

// ---------------------------------------------------------------------------
// Fused 4-dilation conv producing Q (NHWC) = sum_m Sw*(conv_m(xln)+db).
// Block: (wt,h,b); 256 thr = 64 c_out x 4 pixel-quarters (16 px each).
// Weights per-lane in regs (36/ci); input rows staged in LDS, broadcast reads.
// ---------------------------------------------------------------------------
__global__ __launch_bounds__(256) void k_conv(const float* __restrict__ xln,
                                              const float* __restrict__ Wf,
                                              const float* __restrict__ Qb,
                                              float* __restrict__ Q) {
    int wt = blockIdx.x, h = blockIdx.y, b = blockIdx.z;
    int t = threadIdx.x, c = t & 63, q = t >> 6;
    __shared__ float tile[9 * 80];   // 9 needed rows (h±{0,2,4,6,8}) x 80 cols
    float acc[16];
    float qb = Qb[b * 64 + c];
#pragma unroll
    for (int p = 0; p < 16; ++p) acc[p] = qb;
    int w0 = wt * 64;
    for (int ci = 0; ci < 64; ++ci) {
        const float* src = xln + (size_t)(b * 64 + ci) * HWp;
        for (int idx = t; idx < 720; idx += 256) {
            int rr = idx / 80, cc = idx % 80;
            int gh = h + 2 * rr - 8;
            int gw = w0 - 8 + cc;
            float val = 0.f;
            if (gh >= 0 && gh < NH && gw >= 0 && gw < NW) val = src[gh * NW + gw];
            tile[idx] = val;
        }
        __syncthreads();
        const float* wp = Wf + (size_t)((b * 64 + ci) * 64 + c) * 36;
        float wreg[36];
#pragma unroll
        for (int k = 0; k < 9; ++k) {
            float4 f = ((const float4*)wp)[k];
            wreg[4 * k] = f.x; wreg[4 * k + 1] = f.y; wreg[4 * k + 2] = f.z; wreg[4 * k + 3] = f.w;
        }
        int xb = 8 + q * 16;
#pragma unroll
        for (int m = 0; m < 4; ++m) {
            int d = 2 * (m + 1);
#pragma unroll
            for (int kh = 0; kh < 3; ++kh) {
                const float* row = tile + (4 + (m + 1) * (kh - 1)) * 80;
#pragma unroll
                for (int kw = 0; kw < 3; ++kw) {
                    float wv = wreg[m * 9 + kh * 3 + kw];
                    const float* pp = row + xb + d * (kw - 1);
#pragma unroll
                    for (int p2 = 0; p2 < 8; ++p2) {
                        float2 in2 = *(const float2*)(pp + 2 * p2);   // even offset -> 8B aligned
                        acc[2 * p2]     += wv * in2.x;
                        acc[2 * p2 + 1] += wv * in2.y;
                    }
                }
            }
        }
        __syncthreads();
    }
    float* qp = Q + ((size_t)(b * NH + h) * NW + w0 + q * 16) * 64 + c;
#pragma unroll
    for (int p = 0; p < 16; ++p) qp[p * 64] = acc[p];
}

// ---------------------------------------------------------------------------
// 1x1 conv V = x @ w2^T + b2, NHWC output.
// ---------------------------------------------------------------------------
__global__ __launch_bounds__(256) void k_v(const float* __restrict__ x,
                                           const float* __restrict__ w2,
                                           const float* __restrict__ b2,
                                           float* __restrict__ V) {
    int wt = blockIdx.x, h = blockIdx.y, b = blockIdx.z;
    int t = threadIdx.x, c = t & 63, q = t >> 6;
    __shared__ float xs[64 * 64];
    int w0 = wt * 64;
    const float* src = x + (size_t)(b * 64) * HWp + h * NW + w0;
    for (int idx = t; idx < 4096; idx += 256) {
        int ci = idx >> 6, col = idx & 63;
        xs[idx] = src[(size_t)ci * HWp + col];
    }
    float wreg[64];
    const float* wrow = w2 + c * 64;
#pragma unroll
    for (int k = 0; k < 16; ++k) {
        float4 f = ((const float4*)wrow)[k];
        wreg[4 * k] = f.x; wreg[4 * k + 1] = f.y; wreg[4 * k + 2] = f.z; wreg[4 * k + 3] = f.w;
    }
    __syncthreads();
    float acc[16];
    float bias = b2[c];
#pragma unroll
    for (int p = 0; p < 16; ++p) acc[p] = bias;
#pragma unroll
    for (int ci = 0; ci < 64; ++ci) {
        float wv = wreg[ci];
        const float* xrow = xs + ci * 64 + q * 16;
#pragma unroll
        for (int p2 = 0; p2 < 8; ++p2) {
            float2 in2 = *(const float2*)(xrow + 2 * p2);
            acc[2 * p2]     += wv * in2.x;
            acc[2 * p2 + 1] += wv * in2.y;
        }
    }
    float* vp = V + ((size_t)(b * NH + h) * NW + w0 + q * 16) * 64 + c;
#pragma unroll
    for (int p = 0; p < 16; ++p) vp[p * 64] = acc[p];
}

// ---------------------------------------------------------------------------
// Score tiles: attn[b,h,w,v] = (Ql[w]·Qr[v]) * C^-0.5, 64x64 tile per block.
// ---------------------------------------------------------------------------
__global__ __launch_bounds__(256) void k_score(const float* __restrict__ Ql,
                                               const float* __restrict__ Qr,
                                               float* __restrict__ attn) {
    int wt = blockIdx.x >> 2, vt = blockIdx.x & 3;
    int h = blockIdx.y, b = blockIdx.z;
    int t = threadIdx.x, lane = t & 63, g = t >> 6;
    __shared__ float QwT[64 * 64], QvT[64 * 64], SL[64 * 65];
    const float* qlbase = Ql + ((size_t)(b * NH + h) * NW + wt * 64) * 64;
    const float* qrbase = Qr + ((size_t)(b * NH + h) * NW + vt * 64) * 64;
#pragma unroll
    for (int k = 0; k < 4; ++k) {
        int c4 = (g + k * 4) * 4;
        float4 f = *(const float4*)(qlbase + lane * 64 + c4);
        QwT[(c4 + 0) * 64 + lane] = f.x; QwT[(c4 + 1) * 64 + lane] = f.y;
        QwT[(c4 + 2) * 64 + lane] = f.z; QwT[(c4 + 3) * 64 + lane] = f.w;
        float4 fr = *(const float4*)(qrbase + lane * 64 + c4);
        QvT[(c4 + 0) * 64 + lane] = fr.x; QvT[(c4 + 1) * 64 + lane] = fr.y;
        QvT[(c4 + 2) * 64 + lane] = fr.z; QvT[(c4 + 3) * 64 + lane] = fr.w;
    }
    __syncthreads();
    float s16[16];
#pragma unroll
    for (int i = 0; i < 16; ++i) s16[i] = 0.f;
    for (int cc = 0; cc < 64; ++cc) {
        float qv = QvT[cc * 64 + lane];             // lane = v_local (consecutive)
        const float* wrow = QwT + cc * 64 + g * 16; // broadcast reads
#pragma unroll
        for (int i = 0; i < 16; i += 4) {
            float4 f = *(const float4*)(wrow + i);
            s16[i]     += qv * f.x; s16[i + 1] += qv * f.y;
            s16[i + 2] += qv * f.z; s16[i + 3] += qv * f.w;
        }
    }
#pragma unroll
    for (int i = 0; i < 16; ++i) SL[(g * 16 + i) * 65 + lane] = s16[i] * 0.125f;
    __syncthreads();
    float* abase = attn + ((size_t)(b * NH + h) * NW + wt * 64) * NW + vt * 64;
    for (int idx = t; idx < 4096; idx += 256) {
        int wl = idx >> 6, vv = idx & 63;
        abase[(size_t)wl * NW + vv] = SL[wl * 65 + vv];
    }
}

// ---------------------------------------------------------------------------
// Softmax stats: rows (axis=-1) -> M1,L1inv ; cols (axis=-2) -> M2,L2inv.
// ---------------------------------------------------------------------------
__global__ __launch_bounds__(256) void k_stats(const float* __restrict__ attn,
                                               float* __restrict__ M1, float* __restrict__ L1,
                                               float* __restrict__ M2, float* __restrict__ L2) {
    int qt = blockIdx.x, h = blockIdx.y, b = blockIdx.z;
    int t = threadIdx.x, lane = t & 63, g = t >> 6;
    __shared__ float sm[4][64], sl[4][64];
    const float* abase = attn + (size_t)(b * NH + h) * NW * NW;
    // rows: wave per row
    for (int r = g; r < 64; r += 4) {
        int w = qt * 64 + r;
        const float* row = abase + (size_t)w * NW;
        float vals[4];
        float mx = -1e30f;
#pragma unroll
        for (int k = 0; k < 4; ++k) { vals[k] = row[k * 64 + lane]; mx = fmaxf(mx, vals[k]); }
#pragma unroll
        for (int o = 32; o; o >>= 1) mx = fmaxf(mx, __shfl_xor(mx, o, 64));
        float sum = 0.f;
#pragma unroll
        for (int k = 0; k < 4; ++k) sum += __expf(vals[k] - mx);
#pragma unroll
        for (int o = 32; o; o >>= 1) sum += __shfl_xor(sum, o, 64);
        if (lane == 0) { M1[(b * NH + h) * NW + w] = mx; L1[(b * NH + h) * NW + w] = 1.f / sum; }
    }
    // cols: thread (v=lane) online over w in g-range, merge 4 groups
    {
        int v = qt * 64 + lane;
        float mx = -1e30f, l = 0.f;
        for (int w = g * 64; w < (g + 1) * 64; ++w) {
            float s = abase[(size_t)w * NW + v];
            if (s > mx) { l = l * __expf(mx - s) + 1.f; mx = s; }
            else l += __expf(s - mx);
        }
        sm[g][lane] = mx; sl[g][lane] = l;
        __syncthreads();
        if (g == 0) {
            float Mx = fmaxf(fmaxf(sm[0][lane], sm[1][lane]), fmaxf(sm[2][lane], sm[3][lane]));
            float L = 0.f;
#pragma unroll
            for (int k = 0; k < 4; ++k) L += sl[k][lane] * __expf(sm[k][lane] - Mx);
            M2[(b * NH + h) * NW + v] = Mx;
            L2[(b * NH + h) * NW + v] = 1.f / L;
        }
    }
}

// ---------------------------------------------------------------------------
// out_l = x_l + beta * softmax_row(attn) @ Vr     (NCHW, coalesced stores)
// Block (wc,h,b): 64 rows w; thread (lane,g) owns (w=lane, c=g*16..) accs.
// ---------------------------------------------------------------------------
__global__ __launch_bounds__(256) void k_out1(const float* __restrict__ attn,
                                              const float* __restrict__ Vv,
                                              const float* __restrict__ M1, const float* __restrict__ L1,
                                              const float* __restrict__ xres, const float* __restrict__ bvec,
                                              float* __restrict__ out) {
    int wc = blockIdx.x, h = blockIdx.y, b = blockIdx.z;
    int t = threadIdx.x, lane = t & 63, g = t >> 6;
    __shared__ float Ms[64], Ls[64], PL[64 * 65], VS[64 * 64];
    const float* abase = attn + ((size_t)(b * NH + h) * NW + wc * 64) * NW;
    if (t < 64) {
        Ms[t] = M1[(b * NH + h) * NW + wc * 64 + t];
        Ls[t] = L1[(b * NH + h) * NW + wc * 64 + t];
    }
    float oc[16];
#pragma unroll
    for (int i = 0; i < 16; ++i) oc[i] = 0.f;
    for (int vg = 0; vg < 4; ++vg) {
        __syncthreads();
        const float* vsrc = Vv + ((size_t)(b * NH + h) * NW + vg * 64) * 64;
        for (int idx = t; idx < 4096; idx += 256) VS[idx] = vsrc[idx];
#pragma unroll
        for (int k = 0; k < 16; ++k) {
            int wl = g * 16 + k;
            float s = abase[(size_t)wl * NW + vg * 64 + lane];
            PL[wl * 65 + lane] = __expf(s - Ms[wl]) * Ls[wl];
        }
        __syncthreads();
        for (int v = 0; v < 64; ++v) {
            float pv = PL[lane * 65 + v];
            const float4* vp = (const float4*)(VS + v * 64 + g * 16);
            float4 a0 = vp[0], a1 = vp[1], a2 = vp[2], a3 = vp[3];
            oc[0] += pv * a0.x; oc[1] += pv * a0.y; oc[2]  += pv * a0.z; oc[3]  += pv * a0.w;
            oc[4] += pv * a1.x; oc[5] += pv * a1.y; oc[6]  += pv * a1.z; oc[7]  += pv * a1.w;
            oc[8] += pv * a2.x; oc[9] += pv * a2.y; oc[10] += pv * a2.z; oc[11] += pv * a2.w;
            oc[12] += pv * a3.x; oc[13] += pv * a3.y; oc[14] += pv * a3.z; oc[15] += pv * a3.w;
        }
    }
#pragma unroll
    for (int cc = 0; cc < 16; ++cc) {
        int c = g * 16 + cc;
        size_t o = ((size_t)(b * 64 + c) * NH + h) * NW + wc * 64 + lane;
        out[o] = xres[o] + oc[cc] * bvec[c];
    }
}

// ---------------------------------------------------------------------------
// out_r = x_r + gamma * softmax_col(attn)^T @ Vl   (accumulate over w)
// ---------------------------------------------------------------------------
__global__ __launch_bounds__(256) void k_out2(const float* __restrict__ attn,
                                              const float* __restrict__ Vv,
                                              const float* __restrict__ M2, const float* __restrict__ L2,
                                              const float* __restrict__ xres, const float* __restrict__ bvec,
                                              float* __restrict__ out) {
    int vc = blockIdx.x, h = blockIdx.y, b = blockIdx.z;
    int t = threadIdx.x, lane = t & 63, g = t >> 6;
    __shared__ float Ms[64], Ls[64], PL[64 * 65], VS[64 * 64];
    const float* abase = attn + (size_t)(b * NH + h) * NW * NW + vc * 64;
    if (t < 64) {
        Ms[t] = M2[(b * NH + h) * NW + vc * 64 + t];
        Ls[t] = L2[(b * NH + h) * NW + vc * 64 + t];
    }
    float oc[16];
#pragma unroll
    for (int i = 0; i < 16; ++i) oc[i] = 0.f;
    for (int wg = 0; wg < 4; ++wg) {
        __syncthreads();
        const float* vsrc = Vv + ((size_t)(b * NH + h) * NW + wg * 64) * 64;
        for (int idx = t; idx < 4096; idx += 256) VS[idx] = vsrc[idx];
#pragma unroll
        for (int k = 0; k < 16; ++k) {
            int wl = g * 16 + k;
            float s = abase[(size_t)(wg * 64 + wl) * NW + lane];
            PL[wl * 65 + lane] = __expf(s - Ms[lane]) * Ls[lane];
        }
        __syncthreads();
        for (int w = 0; w < 64; ++w) {
            float pv = PL[w * 65 + lane];
            const float4* vp = (const float4*)(VS + w * 64 + g * 16);
            float4 a0 = vp[0], a1 = vp[1], a2 = vp[2], a3 = vp[3];
            oc[0] += pv * a0.x; oc[1] += pv * a0.y; oc[2]  += pv * a0.z; oc[3]  += pv * a0.w;
            oc[4] += pv * a1.x; oc[5] += pv * a1.y; oc[6]  += pv * a1.z; oc[7]  += pv * a1.w;
            oc[8] += pv * a2.x; oc[9] += pv * a2.y; oc[10] += pv * a2.z; oc[11] += pv * a2.w;
            oc[12] += pv * a3.x; oc[13] += pv * a3.y; oc[14] += pv * a3.z; oc[15] += pv * a3.w;
        }
    }
#pragma unroll
    for (int cc = 0; cc < 16; ++cc) {
        int c = g * 16 + cc;
        size_t o = ((size_t)(b * 64 + c) * NH + h) * NW + vc * 64 + lane;
        out[o] = xres[o] + oc[cc] * bvec[c];
    }
}

// ---------------------------------------------------------------------------
extern "C" void kernel_launch(void* const* d_in, const int* in_sizes, int n_in,
                              void* d_out, int out_size, void* d_ws, size_t ws_size,
                              hipStream_t stream) {
    const float* x_l   = (const float*)d_in[0];
    const float* x_r   = (const float*)d_in[1];
    const float* lnl_g = (const float*)d_in[2];
    const float* lnl_b = (const float*)d_in[3];
    const float* lnr_g = (const float*)d_in[4];
    const float* lnr_b = (const float*)d_in[5];
    const float* l_dw  = (const float*)d_in[6];
    const float* l_db  = (const float*)d_in[7];
    const float* l_c1w = (const float*)d_in[8];
    const float* l_c1b = (const float*)d_in[9];
    const float* l_pw  = (const float*)d_in[10];
    const float* r_dw  = (const float*)d_in[11];
    const float* r_db  = (const float*)d_in[12];
    const float* r_c1w = (const float*)d_in[13];
    const float* r_c1b = (const float*)d_in[14];
    const float* r_pw  = (const float*)d_in[15];
    const float* l2w   = (const float*)d_in[16];
    const float* l2b   = (const float*)d_in[17];
    const float* r2w   = (const float*)d_in[18];
    const float* r2b   = (const float*)d_in[19];
    const float* beta  = (const float*)d_in[20];
    const float* gamma = (const float*)d_in[21];
    float* out = (float*)d_out;

    constexpr size_t PLANE = (size_t)NB * NC * NH * NW;   // 6291456
    float* ws = (float*)d_ws;
    float* XLN = ws;                 ws += PLANE;
    float* QL  = ws;                 ws += PLANE;
    float* QR  = ws;                 ws += PLANE;
    float* VL  = ws;                 ws += PLANE;
    float* VR  = ws;                 ws += PLANE;
    float* ATT = ws;                 ws += (size_t)NB * NH * NW * NW;  // 25165824
    float* WF  = ws;                 ws += 589824;
    float* Tb  = ws;                 ws += 9216;
    float* SW  = ws;                 ws += 1024;
    float* QB  = ws;                 ws += 256;
    float* M1b = ws;                 ws += NB * NH * NW;
    float* L1b = ws;                 ws += NB * NH * NW;
    float* M2b = ws;                 ws += NB * NH * NW;
    float* L2b = ws;                 ws += NB * NH * NW;

    dim3 blk(256);
    // --- left SKM ---
    k_ln    <<<dim3(NH, NB), blk, 0, stream>>>(x_l, lnl_g, lnl_b, XLN);
    k_rect  <<<dim3(NB * NC), blk, 0, stream>>>(XLN, Tb);
    k_select<<<dim3(1), blk, 0, stream>>>(Tb, l_dw, l_db, l_c1w, l_c1b, l_pw, SW, QB);
    k_fold  <<<dim3(2304), blk, 0, stream>>>(l_dw, SW, WF);
    k_conv  <<<dim3(4, NH, NB), blk, 0, stream>>>(XLN, WF, QB, QL);
    k_v     <<<dim3(4, NH, NB), blk, 0, stream>>>(x_l, l2w, l2b, VL);
    // --- right SKM ---
    k_ln    <<<dim3(NH, NB), blk, 0, stream>>>(x_r, lnr_g, lnr_b, XLN);
    k_rect  <<<dim3(NB * NC), blk, 0, stream>>>(XLN, Tb);
    k_select<<<dim3(1), blk, 0, stream>>>(Tb, r_dw, r_db, r_c1w, r_c1b, r_pw, SW, QB);
    k_fold  <<<dim3(2304), blk, 0, stream>>>(r_dw, SW, WF);
    k_conv  <<<dim3(4, NH, NB), blk, 0, stream>>>(XLN, WF, QB, QR);
    k_v     <<<dim3(4, NH, NB), blk, 0, stream>>>(x_r, r2w, r2b, VR);
    // --- cross attention ---
    k_score <<<dim3(16, NH, NB), blk, 0, stream>>>(QL, QR, ATT);
    k_stats <<<dim3(4, NH, NB), blk, 0, stream>>>(ATT, M1b, L1b, M2b, L2b);
    k_out1  <<<dim3(4, NH, NB), blk, 0, stream>>>(ATT, VR, M1b, L1b, x_l, beta, out);
    k_out2  <<<dim3(4, NH, NB), blk, 0, stream>>>(ATT, VL, M2b, L2b, x_r, gamma, out + PLANE);
}

// Round 2
// 1003.775 us; speedup vs baseline: 1.6225x; 1.6225x over previous
//
#include <hip/hip_runtime.h>
#include <hip/hip_bf16.h>
#include <cstdint>

// Problem constants (B,C,H,W fixed by setup_inputs)
constexpr int NB = 4;
constexpr int NC = 64;
constexpr int NH = 96;
constexpr int NW = 256;
constexpr int HWp = NH * NW;          // 24576 pixels per plane
constexpr float EPS = 1e-6f;

typedef __attribute__((ext_vector_type(8))) short short8;
typedef __attribute__((ext_vector_type(4))) short short4t;
typedef __attribute__((ext_vector_type(4))) float f32x4;

static __device__ __forceinline__ short f2bf(float f) {
    __hip_bfloat16 h = __float2bfloat16(f);
    return *reinterpret_cast<short*>(&h);
}

// ---------------------------------------------------------------------------
// LayerNorm2d over channels at each (b,h,w). Block = one (b,h) row, 256 thr.
// ---------------------------------------------------------------------------
__global__ __launch_bounds__(256) void k_ln(const float* __restrict__ x,
                                            const float* __restrict__ g,
                                            const float* __restrict__ bta,
                                            float* __restrict__ out) {
    int h = blockIdx.x, b = blockIdx.y, w = threadIdx.x;
    const float* xp = x + ((size_t)b * NC * NH + h) * NW + w;
    float v[64];
    float s = 0.f, sq = 0.f;
#pragma unroll
    for (int c = 0; c < 64; ++c) {
        float t = xp[(size_t)c * HWp];
        v[c] = t; s += t; sq += t * t;
    }
    float mu = s * (1.f / 64.f);
    float var = sq * (1.f / 64.f) - mu * mu;
    float rs = rsqrtf(var + EPS);
    float* op = out + ((size_t)b * NC * NH + h) * NW + w;
#pragma unroll
    for (int c = 0; c < 64; ++c) op[(size_t)c * HWp] = (v[c] - mu) * rs * g[c] + bta[c];
}

// ---------------------------------------------------------------------------
// Rectangle sums for the SKM global pool (D never materialized).
// T layout: [b][m][ci][9]
// ---------------------------------------------------------------------------
__global__ __launch_bounds__(256) void k_rect(const float* __restrict__ xln,
                                              float* __restrict__ T) {
    int bci = blockIdx.x;
    int b = bci >> 6, ci = bci & 63;
    int t = threadIdx.x, lane = t & 63, wv = t >> 6;
    __shared__ float rp[NH][9];
    const float* base = xln + (size_t)bci * HWp;
    for (int r = wv; r < NH; r += 4) {
        float4 vv = *(const float4*)(base + r * NW + lane * 4);
        float a = vv.x + vv.y, bb = vv.z + vv.w;
        float s4 = a + bb;
        float full = s4;
#pragma unroll
        for (int o = 32; o; o >>= 1) full += __shfl_xor(full, o, 64);
        float l0a = __shfl(a, 0, 64),  l0s = __shfl(s4, 0, 64);
        float l1a = __shfl(a, 1, 64),  l1s = __shfl(s4, 1, 64);
        float r63b = __shfl(bb, 63, 64), r63s = __shfl(s4, 63, 64);
        float r62b = __shfl(bb, 62, 64), r62s = __shfl(s4, 62, 64);
        if (lane == 0) {
            rp[r][0] = full;
            rp[r][1] = l0a;  rp[r][2] = l0s;  rp[r][3] = l0s + l1a;  rp[r][4] = l0s + l1s;
            rp[r][5] = r63b; rp[r][6] = r63s; rp[r][7] = r63s + r62b; rp[r][8] = r63s + r62s;
        }
    }
    __syncthreads();
    if (t < 36) {
        int m = t / 9, kh = (t % 9) / 3, kw = t % 3;
        int d = 2 * (m + 1);
        int r0 = (kh == 2) ? d : 0;
        int r1 = (kh == 0) ? NH - d : NH;
        float s = 0.f;
        for (int r = r0; r < r1; ++r) {
            float rowv = rp[r][0];
            if (kw == 0) rowv -= rp[r][5 + m];
            else if (kw == 2) rowv -= rp[r][1 + m];
            s += rowv;
        }
        T[(((b * 4 + m) * 64) + ci) * 9 + kh * 3 + kw] = s;
    }
}

// ---------------------------------------------------------------------------
// SKM selection MLP: Z -> S -> P -> softmax over C -> Sw, plus folded bias.
// ---------------------------------------------------------------------------
__global__ __launch_bounds__(256) void k_select(const float* __restrict__ T,
                                                const float* __restrict__ dw,
                                                const float* __restrict__ db,
                                                const float* __restrict__ c1w,
                                                const float* __restrict__ c1b,
                                                const float* __restrict__ pw,
                                                float* __restrict__ Sw,
                                                float* __restrict__ Qb) {
    int t = threadIdx.x;
    __shared__ float zs[256], ss[512], ps[1024], sw[1024];
    {
        int b = t >> 6, c = t & 63;
        float acc = 0.f, bias = 0.f;
        for (int m = 0; m < 4; ++m) {
            const float* wp = dw + (size_t)(m * 64 + c) * 576;
            const float* tp = T + (size_t)(b * 4 + m) * 576;
            float a2 = 0.f;
            for (int j = 0; j < 576; ++j) a2 += wp[j] * tp[j];
            acc += a2;
            bias += db[m * 64 + c];
        }
        zs[t] = acc * (1.f / (float)HWp) + bias;
    }
    __syncthreads();
    for (int i = t; i < 512; i += 256) {
        int b = i >> 7, j = i & 127;
        float s = c1b[j];
        const float* wrow = c1w + j * 64;
        const float* zb = zs + b * 64;
        for (int c = 0; c < 64; ++c) s += zb[c] * wrow[c];
        ss[i] = fmaxf(s, 0.f);
    }
    __syncthreads();
    for (int i = t; i < 1024; i += 256) {
        int b = i >> 8, rem = i & 255;
        float p = 0.f;
        const float* sb = ss + b * 128;
        for (int j = 0; j < 128; ++j) p += sb[j] * pw[j * 256 + rem];
        ps[i] = p;
    }
    __syncthreads();
    if (t < 16) {
        int b = t >> 2, m = t & 3;
        const float* pp = ps + b * 256 + m * 64;
        float mx = -1e30f;
        for (int c = 0; c < 64; ++c) mx = fmaxf(mx, pp[c]);
        float sum = 0.f;
        for (int c = 0; c < 64; ++c) sum += expf(pp[c] - mx);
        float inv = 1.f / sum;
        for (int c = 0; c < 64; ++c) sw[b * 256 + m * 64 + c] = expf(pp[c] - mx) * inv;
    }
    __syncthreads();
    {
        int b = t >> 6, c = t & 63;
        float qb = 0.f;
#pragma unroll
        for (int m = 0; m < 4; ++m) {
            float s = sw[b * 256 + m * 64 + c];
            Sw[(b * 4 + m) * 64 + c] = s;
            qb += s * db[m * 64 + c];
        }
        Qb[t] = qb;
    }
}

// ---------------------------------------------------------------------------
// Fold Sw into conv weights, bf16, pre-swizzled to MFMA B-fragment order:
// WB[b][chunk(4)][tpair(18)][co(64)][k32], k = tpl*16 + cil,
// tap = 2*tpair+tpl, ci = chunk*16+cil.
// ---------------------------------------------------------------------------
__global__ __launch_bounds__(256) void k_fold(const float* __restrict__ dw,
                                              const float* __restrict__ Sw,
                                              short* __restrict__ WB) {
    int idx = blockIdx.x * 256 + threadIdx.x;   // 589824 total
    int kk = idx & 31;
    int co = (idx >> 5) & 63;
    int rest = idx >> 11;            // [0,288)
    int tpair = rest % 18;
    int bc = rest / 18;              // [0,16)
    int chunk = bc & 3, b = bc >> 2;
    int tpl = kk >> 4, cil = kk & 15;
    int tap = 2 * tpair + tpl;
    int m = tap / 9, k9 = tap % 9;
    int ci = chunk * 16 + cil;
    float val = Sw[(b * 4 + m) * 64 + co] * dw[(size_t)((m * 64 + co) * 64 + ci) * 9 + k9];
    WB[idx] = f2bf(val);
}

// ---------------------------------------------------------------------------
// MFMA implicit-GEMM fused 4-dilation conv -> Q (NHWC).
// Block = 128 thr (2 waves), 128 px of one h-row. Wave: 64px x 64co,
// 4x4 tiles of 16x16x32 bf16 MFMA. K = 4 ci-chunks x 18 tap-pairs x K32.
// A staged in LDS (two ci-half arrays, stride-16B frag reads = conflict-free);
// B read from global L2 in pre-swizzled fragment order.
// ---------------------------------------------------------------------------
__global__ __launch_bounds__(128) void k_convm(const float* __restrict__ xln,
                                               const short* __restrict__ WB,
                                               const float* __restrict__ Qb,
                                               float* __restrict__ Q) {
    const int wt = blockIdx.x, h = blockIdx.y, b = blockIdx.z;
    const int t = threadIdx.x;
    const int lane = t & 63, wave = t >> 6;
    const int g = lane >> 4, ln15 = lane & 15;
    __shared__ short tile[2 * 9 * 144 * 8];   // [half][r][col][ci8]

    f32x4 acc[4][4];
    {
        float qb[4];
#pragma unroll
        for (int nt = 0; nt < 4; ++nt) qb[nt] = Qb[b * 64 + nt * 16 + ln15];
#pragma unroll
        for (int mt = 0; mt < 4; ++mt)
#pragma unroll
            for (int nt = 0; nt < 4; ++nt)
                acc[mt][nt] = (f32x4){qb[nt], qb[nt], qb[nt], qb[nt]};
    }
    const int w0 = wt * 128;
    const int laneelem = (wave * 64 + ln15) * 8;       // pxl*8 (ci8 shorts per col)
    const int halfoff = (g & 1) * (9 * 144 * 8);
    const int tsel = g >> 1;                           // 0 -> tap even, 1 -> tap odd

    for (int chunk = 0; chunk < 4; ++chunk) {
        __syncthreads();
        // stage 9 rows x 144 cols x 16 ci (bf16), ci-halves in separate arrays
        for (int slot = t; slot < 9 * 144 * 4; slot += 128) {
            int col = slot % 144;
            int rc = slot / 144;
            int r = rc % 9;
            int cg = rc / 9;                           // 0..3 -> ci group of 4
            int gh = h + 2 * r - 8;
            int gw = w0 - 8 + col;
            float f0 = 0.f, f1 = 0.f, f2 = 0.f, f3 = 0.f;
            if (gh >= 0 && gh < NH && gw >= 0 && gw < NW) {
                const float* p = xln + ((size_t)(b * 64 + chunk * 16 + cg * 4) * NH + gh) * NW + gw;
                f0 = p[0]; f1 = p[HWp]; f2 = p[2 * HWp]; f3 = p[3 * HWp];
            }
            short4t sv = {f2bf(f0), f2bf(f1), f2bf(f2), f2bf(f3)};
            short* dst = tile + (cg >= 2 ? 9 * 144 * 8 : 0) + (r * 144 + col) * 8 + (cg & 1) * 4;
            *(short4t*)dst = sv;
        }
        __syncthreads();

        const short* wbase = WB + (size_t)((b * 4 + chunk) * 18) * 2048 + ln15 * 32 + g * 8;
        for (int tp = 0; tp < 18; ++tp) {
            int ta = 2 * tp, tb = ta + 1;
            int ma = ta / 9, k9a = ta % 9;
            int mb = tb / 9, k9b = tb % 9;
            int offA = ((4 + (ma + 1) * (k9a / 3 - 1)) * 144 + 8 + 2 * (ma + 1) * (k9a % 3 - 1)) * 8;
            int offB = ((4 + (mb + 1) * (k9b / 3 - 1)) * 144 + 8 + 2 * (mb + 1) * (k9b % 3 - 1)) * 8;
            int aoff = (tsel ? offB : offA) + laneelem + halfoff;
            const short* ap = tile + aoff;
            short8 a0 = *(const short8*)(ap);
            short8 a1 = *(const short8*)(ap + 128);
            short8 a2 = *(const short8*)(ap + 256);
            short8 a3 = *(const short8*)(ap + 384);
            const short* bp = wbase + (size_t)tp * 2048;
            short8 b0 = *(const short8*)(bp);
            short8 b1 = *(const short8*)(bp + 512);
            short8 b2 = *(const short8*)(bp + 1024);
            short8 b3 = *(const short8*)(bp + 1536);
            acc[0][0] = __builtin_amdgcn_mfma_f32_16x16x32_bf16(a0, b0, acc[0][0], 0, 0, 0);
            acc[0][1] = __builtin_amdgcn_mfma_f32_16x16x32_bf16(a0, b1, acc[0][1], 0, 0, 0);
            acc[0][2] = __builtin_amdgcn_mfma_f32_16x16x32_bf16(a0, b2, acc[0][2], 0, 0, 0);
            acc[0][3] = __builtin_amdgcn_mfma_f32_16x16x32_bf16(a0, b3, acc[0][3], 0, 0, 0);
            acc[1][0] = __builtin_amdgcn_mfma_f32_16x16x32_bf16(a1, b0, acc[1][0], 0, 0, 0);
            acc[1][1] = __builtin_amdgcn_mfma_f32_16x16x32_bf16(a1, b1, acc[1][1], 0, 0, 0);
            acc[1][2] = __builtin_amdgcn_mfma_f32_16x16x32_bf16(a1, b2, acc[1][2], 0, 0, 0);
            acc[1][3] = __builtin_amdgcn_mfma_f32_16x16x32_bf16(a1, b3, acc[1][3], 0, 0, 0);
            acc[2][0] = __builtin_amdgcn_mfma_f32_16x16x32_bf16(a2, b0, acc[2][0], 0, 0, 0);
            acc[2][1] = __builtin_amdgcn_mfma_f32_16x16x32_bf16(a2, b1, acc[2][1], 0, 0, 0);
            acc[2][2] = __builtin_amdgcn_mfma_f32_16x16x32_bf16(a2, b2, acc[2][2], 0, 0, 0);
            acc[2][3] = __builtin_amdgcn_mfma_f32_16x16x32_bf16(a2, b3, acc[2][3], 0, 0, 0);
            acc[3][0] = __builtin_amdgcn_mfma_f32_16x16x32_bf16(a3, b0, acc[3][0], 0, 0, 0);
            acc[3][1] = __builtin_amdgcn_mfma_f32_16x16x32_bf16(a3, b1, acc[3][1], 0, 0, 0);
            acc[3][2] = __builtin_amdgcn_mfma_f32_16x16x32_bf16(a3, b2, acc[3][2], 0, 0, 0);
            acc[3][3] = __builtin_amdgcn_mfma_f32_16x16x32_bf16(a3, b3, acc[3][3], 0, 0, 0);
        }
    }
    // epilogue: D row=(lane>>4)*4+j (px), col=lane&15 (co)
#pragma unroll
    for (int mt = 0; mt < 4; ++mt) {
        int px = w0 + wave * 64 + mt * 16 + (lane >> 4) * 4;
#pragma unroll
        for (int j = 0; j < 4; ++j) {
            float* qp = Q + ((size_t)(b * NH + h) * NW + px + j) * 64 + ln15;
            qp[0]  = acc[mt][0][j];
            qp[16] = acc[mt][1][j];
            qp[32] = acc[mt][2][j];
            qp[48] = acc[mt][3][j];
        }
    }
}

// ---------------------------------------------------------------------------
// 1x1 conv V = x @ w2^T + b2, NHWC output.
// ---------------------------------------------------------------------------
__global__ __launch_bounds__(256) void k_v(const float* __restrict__ x,
                                           const float* __restrict__ w2,
                                           const float* __restrict__ b2,
                                           float* __restrict__ V) {
    int wt = blockIdx.x, h = blockIdx.y, b = blockIdx.z;
    int t = threadIdx.x, c = t & 63, q = t >> 6;
    __shared__ float xs[64 * 64];
    int w0 = wt * 64;
    const float* src = x + (size_t)(b * 64) * HWp + h * NW + w0;
    for (int idx = t; idx < 4096; idx += 256) {
        int ci = idx >> 6, col = idx & 63;
        xs[idx] = src[(size_t)ci * HWp + col];
    }
    float wreg[64];
    const float* wrow = w2 + c * 64;
#pragma unroll
    for (int k = 0; k < 16; ++k) {
        float4 f = ((const float4*)wrow)[k];
        wreg[4 * k] = f.x; wreg[4 * k + 1] = f.y; wreg[4 * k + 2] = f.z; wreg[4 * k + 3] = f.w;
    }
    __syncthreads();
    float acc[16];
    float bias = b2[c];
#pragma unroll
    for (int p = 0; p < 16; ++p) acc[p] = bias;
#pragma unroll
    for (int ci = 0; ci < 64; ++ci) {
        float wv = wreg[ci];
        const float* xrow = xs + ci * 64 + q * 16;
#pragma unroll
        for (int p2 = 0; p2 < 8; ++p2) {
            float2 in2 = *(const float2*)(xrow + 2 * p2);
            acc[2 * p2]     += wv * in2.x;
            acc[2 * p2 + 1] += wv * in2.y;
        }
    }
    float* vp = V + ((size_t)(b * NH + h) * NW + w0 + q * 16) * 64 + c;
#pragma unroll
    for (int p = 0; p < 16; ++p) vp[p * 64] = acc[p];
}

// ---------------------------------------------------------------------------
// Score tiles: attn[b,h,w,v] = (Ql[w]·Qr[v]) * C^-0.5, 64x64 tile per block.
// ---------------------------------------------------------------------------
__global__ __launch_bounds__(256) void k_score(const float* __restrict__ Ql,
                                               const float* __restrict__ Qr,
                                               float* __restrict__ attn) {
    int wt = blockIdx.x >> 2, vt = blockIdx.x & 3;
    int h = blockIdx.y, b = blockIdx.z;
    int t = threadIdx.x, lane = t & 63, g = t >> 6;
    __shared__ float QwT[64 * 64], QvT[64 * 64], SL[64 * 65];
    const float* qlbase = Ql + ((size_t)(b * NH + h) * NW + wt * 64) * 64;
    const float* qrbase = Qr + ((size_t)(b * NH + h) * NW + vt * 64) * 64;
#pragma unroll
    for (int k = 0; k < 4; ++k) {
        int c4 = (g + k * 4) * 4;
        float4 f = *(const float4*)(qlbase + lane * 64 + c4);
        QwT[(c4 + 0) * 64 + lane] = f.x; QwT[(c4 + 1) * 64 + lane] = f.y;
        QwT[(c4 + 2) * 64 + lane] = f.z; QwT[(c4 + 3) * 64 + lane] = f.w;
        float4 fr = *(const float4*)(qrbase + lane * 64 + c4);
        QvT[(c4 + 0) * 64 + lane] = fr.x; QvT[(c4 + 1) * 64 + lane] = fr.y;
        QvT[(c4 + 2) * 64 + lane] = fr.z; QvT[(c4 + 3) * 64 + lane] = fr.w;
    }
    __syncthreads();
    float s16[16];
#pragma unroll
    for (int i = 0; i < 16; ++i) s16[i] = 0.f;
    for (int cc = 0; cc < 64; ++cc) {
        float qv = QvT[cc * 64 + lane];
        const float* wrow = QwT + cc * 64 + g * 16;
#pragma unroll
        for (int i = 0; i < 16; i += 4) {
            float4 f = *(const float4*)(wrow + i);
            s16[i]     += qv * f.x; s16[i + 1] += qv * f.y;
            s16[i + 2] += qv * f.z; s16[i + 3] += qv * f.w;
        }
    }
#pragma unroll
    for (int i = 0; i < 16; ++i) SL[(g * 16 + i) * 65 + lane] = s16[i] * 0.125f;
    __syncthreads();
    float* abase = attn + ((size_t)(b * NH + h) * NW + wt * 64) * NW + vt * 64;
    for (int idx = t; idx < 4096; idx += 256) {
        int wl = idx >> 6, vv = idx & 63;
        abase[(size_t)wl * NW + vv] = SL[wl * 65 + vv];
    }
}

// ---------------------------------------------------------------------------
// Softmax stats: rows (axis=-1) -> M1,L1inv ; cols (axis=-2) -> M2,L2inv.
// ---------------------------------------------------------------------------
__global__ __launch_bounds__(256) void k_stats(const float* __restrict__ attn,
                                               float* __restrict__ M1, float* __restrict__ L1,
                                               float* __restrict__ M2, float* __restrict__ L2) {
    int qt = blockIdx.x, h = blockIdx.y, b = blockIdx.z;
    int t = threadIdx.x, lane = t & 63, g = t >> 6;
    __shared__ float sm[4][64], sl[4][64];
    const float* abase = attn + (size_t)(b * NH + h) * NW * NW;
    for (int r = g; r < 64; r += 4) {
        int w = qt * 64 + r;
        const float* row = abase + (size_t)w * NW;
        float vals[4];
        float mx = -1e30f;
#pragma unroll
        for (int k = 0; k < 4; ++k) { vals[k] = row[k * 64 + lane]; mx = fmaxf(mx, vals[k]); }
#pragma unroll
        for (int o = 32; o; o >>= 1) mx = fmaxf(mx, __shfl_xor(mx, o, 64));
        float sum = 0.f;
#pragma unroll
        for (int k = 0; k < 4; ++k) sum += __expf(vals[k] - mx);
#pragma unroll
        for (int o = 32; o; o >>= 1) sum += __shfl_xor(sum, o, 64);
        if (lane == 0) { M1[(b * NH + h) * NW + w] = mx; L1[(b * NH + h) * NW + w] = 1.f / sum; }
    }
    {
        int v = qt * 64 + lane;
        float mx = -1e30f, l = 0.f;
        for (int w = g * 64; w < (g + 1) * 64; ++w) {
            float s = abase[(size_t)w * NW + v];
            if (s > mx) { l = l * __expf(mx - s) + 1.f; mx = s; }
            else l += __expf(s - mx);
        }
        sm[g][lane] = mx; sl[g][lane] = l;
        __syncthreads();
        if (g == 0) {
            float Mx = fmaxf(fmaxf(sm[0][lane], sm[1][lane]), fmaxf(sm[2][lane], sm[3][lane]));
            float L = 0.f;
#pragma unroll
            for (int k = 0; k < 4; ++k) L += sl[k][lane] * __expf(sm[k][lane] - Mx);
            M2[(b * NH + h) * NW + v] = Mx;
            L2[(b * NH + h) * NW + v] = 1.f / L;
        }
    }
}

// ---------------------------------------------------------------------------
// out_l = x_l + beta * softmax_row(attn) @ Vr     (NCHW, coalesced stores)
// ---------------------------------------------------------------------------
__global__ __launch_bounds__(256) void k_out1(const float* __restrict__ attn,
                                              const float* __restrict__ Vv,
                                              const float* __restrict__ M1, const float* __restrict__ L1,
                                              const float* __restrict__ xres, const float* __restrict__ bvec,
                                              float* __restrict__ out) {
    int wc = blockIdx.x, h = blockIdx.y, b = blockIdx.z;
    int t = threadIdx.x, lane = t & 63, g = t >> 6;
    __shared__ float Ms[64], Ls[64], PL[64 * 65], VS[64 * 64];
    const float* abase = attn + ((size_t)(b * NH + h) * NW + wc * 64) * NW;
    if (t < 64) {
        Ms[t] = M1[(b * NH + h) * NW + wc * 64 + t];
        Ls[t] = L1[(b * NH + h) * NW + wc * 64 + t];
    }
    float oc[16];
#pragma unroll
    for (int i = 0; i < 16; ++i) oc[i] = 0.f;
    for (int vg = 0; vg < 4; ++vg) {
        __syncthreads();
        const float* vsrc = Vv + ((size_t)(b * NH + h) * NW + vg * 64) * 64;
        for (int idx = t; idx < 4096; idx += 256) VS[idx] = vsrc[idx];
#pragma unroll
        for (int k = 0; k < 16; ++k) {
            int wl = g * 16 + k;
            float s = abase[(size_t)wl * NW + vg * 64 + lane];
            PL[wl * 65 + lane] = __expf(s - Ms[wl]) * Ls[wl];
        }
        __syncthreads();
        for (int v = 0; v < 64; ++v) {
            float pv = PL[lane * 65 + v];
            const float4* vp = (const float4*)(VS + v * 64 + g * 16);
            float4 a0 = vp[0], a1 = vp[1], a2 = vp[2], a3 = vp[3];
            oc[0] += pv * a0.x; oc[1] += pv * a0.y; oc[2]  += pv * a0.z; oc[3]  += pv * a0.w;
            oc[4] += pv * a1.x; oc[5] += pv * a1.y; oc[6]  += pv * a1.z; oc[7]  += pv * a1.w;
            oc[8] += pv * a2.x; oc[9] += pv * a2.y; oc[10] += pv * a2.z; oc[11] += pv * a2.w;
            oc[12] += pv * a3.x; oc[13] += pv * a3.y; oc[14] += pv * a3.z; oc[15] += pv * a3.w;
        }
    }
#pragma unroll
    for (int cc = 0; cc < 16; ++cc) {
        int c = g * 16 + cc;
        size_t o = ((size_t)(b * 64 + c) * NH + h) * NW + wc * 64 + lane;
        out[o] = xres[o] + oc[cc] * bvec[c];
    }
}

// ---------------------------------------------------------------------------
// out_r = x_r + gamma * softmax_col(attn)^T @ Vl   (accumulate over w)
// ---------------------------------------------------------------------------
__global__ __launch_bounds__(256) void k_out2(const float* __restrict__ attn,
                                              const float* __restrict__ Vv,
                                              const float* __restrict__ M2, const float* __restrict__ L2,
                                              const float* __restrict__ xres, const float* __restrict__ bvec,
                                              float* __restrict__ out) {
    int vc = blockIdx.x, h = blockIdx.y, b = blockIdx.z;
    int t = threadIdx.x, lane = t & 63, g = t >> 6;
    __shared__ float Ms[64], Ls[64], PL[64 * 65], VS[64 * 64];
    const float* abase = attn + (size_t)(b * NH + h) * NW * NW + vc * 64;
    if (t < 64) {
        Ms[t] = M2[(b * NH + h) * NW + vc * 64 + t];
        Ls[t] = L2[(b * NH + h) * NW + vc * 64 + t];
    }
    float oc[16];
#pragma unroll
    for (int i = 0; i < 16; ++i) oc[i] = 0.f;
    for (int wg = 0; wg < 4; ++wg) {
        __syncthreads();
        const float* vsrc = Vv + ((size_t)(b * NH + h) * NW + wg * 64) * 64;
        for (int idx = t; idx < 4096; idx += 256) VS[idx] = vsrc[idx];
#pragma unroll
        for (int k = 0; k < 16; ++k) {
            int wl = g * 16 + k;
            float s = abase[(size_t)(wg * 64 + wl) * NW + lane];
            PL[wl * 65 + lane] = __expf(s - Ms[lane]) * Ls[lane];
        }
        __syncthreads();
        for (int w = 0; w < 64; ++w) {
            float pv = PL[w * 65 + lane];
            const float4* vp = (const float4*)(VS + w * 64 + g * 16);
            float4 a0 = vp[0], a1 = vp[1], a2 = vp[2], a3 = vp[3];
            oc[0] += pv * a0.x; oc[1] += pv * a0.y; oc[2]  += pv * a0.z; oc[3]  += pv * a0.w;
            oc[4] += pv * a1.x; oc[5] += pv * a1.y; oc[6]  += pv * a1.z; oc[7]  += pv * a1.w;
            oc[8] += pv * a2.x; oc[9] += pv * a2.y; oc[10] += pv * a2.z; oc[11] += pv * a2.w;
            oc[12] += pv * a3.x; oc[13] += pv * a3.y; oc[14] += pv * a3.z; oc[15] += pv * a3.w;
        }
    }
#pragma unroll
    for (int cc = 0; cc < 16; ++cc) {
        int c = g * 16 + cc;
        size_t o = ((size_t)(b * 64 + c) * NH + h) * NW + vc * 64 + lane;
        out[o] = xres[o] + oc[cc] * bvec[c];
    }
}

// ---------------------------------------------------------------------------
extern "C" void kernel_launch(void* const* d_in, const int* in_sizes, int n_in,
                              void* d_out, int out_size, void* d_ws, size_t ws_size,
                              hipStream_t stream) {
    const float* x_l   = (const float*)d_in[0];
    const float* x_r   = (const float*)d_in[1];
    const float* lnl_g = (const float*)d_in[2];
    const float* lnl_b = (const float*)d_in[3];
    const float* lnr_g = (const float*)d_in[4];
    const float* lnr_b = (const float*)d_in[5];
    const float* l_dw  = (const float*)d_in[6];
    const float* l_db  = (const float*)d_in[7];
    const float* l_c1w = (const float*)d_in[8];
    const float* l_c1b = (const float*)d_in[9];
    const float* l_pw  = (const float*)d_in[10];
    const float* r_dw  = (const float*)d_in[11];
    const float* r_db  = (const float*)d_in[12];
    const float* r_c1w = (const float*)d_in[13];
    const float* r_c1b = (const float*)d_in[14];
    const float* r_pw  = (const float*)d_in[15];
    const float* l2w   = (const float*)d_in[16];
    const float* l2b   = (const float*)d_in[17];
    const float* r2w   = (const float*)d_in[18];
    const float* r2b   = (const float*)d_in[19];
    const float* beta  = (const float*)d_in[20];
    const float* gamma = (const float*)d_in[21];
    float* out = (float*)d_out;

    constexpr size_t PLANE = (size_t)NB * NC * NH * NW;   // 6291456
    float* ws = (float*)d_ws;
    float* XLN = ws;                 ws += PLANE;
    float* QL  = ws;                 ws += PLANE;
    float* QR  = ws;                 ws += PLANE;
    float* VL  = ws;                 ws += PLANE;
    float* VR  = ws;                 ws += PLANE;
    float* ATT = ws;                 ws += (size_t)NB * NH * NW * NW;  // 25165824
    short* WB  = (short*)ws;         ws += 294912;   // 589824 bf16
    float* Tb  = ws;                 ws += 9216;
    float* SW  = ws;                 ws += 1024;
    float* QB  = ws;                 ws += 256;
    float* M1b = ws;                 ws += NB * NH * NW;
    float* L1b = ws;                 ws += NB * NH * NW;
    float* M2b = ws;                 ws += NB * NH * NW;
    float* L2b = ws;                 ws += NB * NH * NW;

    dim3 blk(256);
    // --- left SKM ---
    k_ln    <<<dim3(NH, NB), blk, 0, stream>>>(x_l, lnl_g, lnl_b, XLN);
    k_rect  <<<dim3(NB * NC), blk, 0, stream>>>(XLN, Tb);
    k_select<<<dim3(1), blk, 0, stream>>>(Tb, l_dw, l_db, l_c1w, l_c1b, l_pw, SW, QB);
    k_fold  <<<dim3(2304), blk, 0, stream>>>(l_dw, SW, WB);
    k_convm <<<dim3(2, NH, NB), dim3(128), 0, stream>>>(XLN, WB, QB, QL);
    k_v     <<<dim3(4, NH, NB), blk, 0, stream>>>(x_l, l2w, l2b, VL);
    // --- right SKM ---
    k_ln    <<<dim3(NH, NB), blk, 0, stream>>>(x_r, lnr_g, lnr_b, XLN);
    k_rect  <<<dim3(NB * NC), blk, 0, stream>>>(XLN, Tb);
    k_select<<<dim3(1), blk, 0, stream>>>(Tb, r_dw, r_db, r_c1w, r_c1b, r_pw, SW, QB);
    k_fold  <<<dim3(2304), blk, 0, stream>>>(r_dw, SW, WB);
    k_convm <<<dim3(2, NH, NB), dim3(128), 0, stream>>>(XLN, WB, QB, QR);
    k_v     <<<dim3(4, NH, NB), blk, 0, stream>>>(x_r, r2w, r2b, VR);
    // --- cross attention ---
    k_score <<<dim3(16, NH, NB), blk, 0, stream>>>(QL, QR, ATT);
    k_stats <<<dim3(4, NH, NB), blk, 0, stream>>>(ATT, M1b, L1b, M2b, L2b);
    k_out1  <<<dim3(4, NH, NB), blk, 0, stream>>>(ATT, VR, M1b, L1b, x_l, beta, out);
    k_out2  <<<dim3(4, NH, NB), blk, 0, stream>>>(ATT, VL, M2b, L2b, x_r, gamma, out + PLANE);
}